// Round 6
// baseline (470.811 us; speedup 1.0000x reference)
//
#include <hip/hip_runtime.h>
#include <hip/hip_bf16.h>
#include <hip/hip_cooperative_groups.h>

#define NSEQ 4096
#define CDIM 256
#define CQKD 32
#define LOG2E 1.4426950408889634f

typedef float v4f __attribute__((ext_vector_type(4)));
typedef float v16f __attribute__((ext_vector_type(16)));
typedef short v8s __attribute__((ext_vector_type(8)));
typedef unsigned long long u64;

__device__ __forceinline__ float exp2_(float x) {
#if __has_builtin(__builtin_amdgcn_exp2f)
  return __builtin_amdgcn_exp2f(x);
#else
  float r;
  __asm__("v_exp_f32 %0, %1" : "=v"(r) : "v"(x));
  return r;
#endif
}

__device__ __forceinline__ unsigned short f2bf(float x) {
  unsigned u = __builtin_bit_cast(unsigned, x);
  unsigned r = (u + 0x7FFFu + ((u >> 16) & 1u)) >> 16;
  return (unsigned short)r;
}
__device__ __forceinline__ float bf2f(unsigned short s) {
  unsigned u = ((unsigned)s) << 16;
  return __builtin_bit_cast(float, u);
}
__device__ __forceinline__ unsigned int pack_bf16(float a, float b) {
#if __has_builtin(__builtin_amdgcn_cvt_pk_bf16_f32)
  typedef __bf16 v2bf __attribute__((ext_vector_type(2)));
  v2bf r = __builtin_amdgcn_cvt_pk_bf16_f32(a, b);
  return __builtin_bit_cast(unsigned int, r);
#else
  return ((unsigned)f2bf(b) << 16) | (unsigned)f2bf(a);
#endif
}

// fp8 e4m3fn (OCP) encode, software fallback
__device__ __forceinline__ unsigned char f2e4m3(float x) {
  unsigned u = __builtin_bit_cast(unsigned, x);
  unsigned s = (u >> 24) & 0x80u;
  unsigned au = u & 0x7fffffffu;
  if (au > 0x43e00000u) return (unsigned char)(s | 0x7eu);  // clamp to 448
  if (au < 0x3c800000u) {                                   // subnormal range (<2^-6)
    float ax = __builtin_bit_cast(float, au);
    int q = (int)(ax * 512.0f + 0.5f);
    if (q > 7) q = 7;
    return (unsigned char)(s | (unsigned)q);
  }
  int e = (int)((au >> 23) & 0xffu) - 127 + 7;
  unsigned m = au & 0x7fffffu;
  unsigned mr = m + 0x7ffffu + ((m >> 20) & 1u);
  if (mr >= 0x800000u) { mr -= 0x800000u; e += 1; if (e >= 16) return (unsigned char)(s | 0x7e); }
  return (unsigned char)(s | ((unsigned)e << 3) | (mr >> 20));
}
__device__ __forceinline__ unsigned int pack4_fp8(float a, float b, float c, float d) {
#if __has_builtin(__builtin_amdgcn_cvt_pk_fp8_f32)
  int v = 0;
  v = __builtin_amdgcn_cvt_pk_fp8_f32(a, b, v, false);
  v = __builtin_amdgcn_cvt_pk_fp8_f32(c, d, v, true);
  return (unsigned int)v;
#else
  return (unsigned)f2e4m3(a) | ((unsigned)f2e4m3(b) << 8) |
         ((unsigned)f2e4m3(c) << 16) | ((unsigned)f2e4m3(d) << 24);
#endif
}

// LDS-only split barrier (orders LDS producer->consumer without draining vmcnt)
__device__ __forceinline__ void barrier_lds() {
  __asm__ __volatile__("s_waitcnt lgkmcnt(0)\n\ts_barrier" ::: "memory");
}

// ---------------- attention phase helpers (round-5 structure, unchanged) ----------------
__device__ __forceinline__ void max_pass16(
    const unsigned short* __restrict__ Kp, const v8s qf[4], int w, int lane,
    float (*lbuf)[64], float m[4]) {
  const v4f vzero4 = {0.f, 0.f, 0.f, 0.f};
  const int r15 = lane & 15;
  const unsigned short* Kl = Kp + (size_t)w * 512 + lane * 8;
  v8s kA = *(const v8s*)(Kl);
  v8s kB = *(const v8s*)(Kl + 8192);
#pragma unroll
  for (int qt = 0; qt < 4; ++qt) m[qt] = -3.0e38f;
#pragma unroll 2
  for (int kt = 0; kt < 16; ++kt) {
    v8s kC = *(const v8s*)(Kl + (size_t)((kt + 2) & 15) * 8192);  // depth-2 prefetch
#pragma unroll
    for (int qt = 0; qt < 4; ++qt) {
      v4f st = __builtin_amdgcn_mfma_f32_16x16x32_bf16(kA, qf[qt], vzero4, 0, 0, 0);
      m[qt] = fmaxf(m[qt], fmaxf(fmaxf(st[0], st[1]), fmaxf(st[2], st[3])));
    }
    kA = kB;
    kB = kC;
  }
#pragma unroll
  for (int qt = 0; qt < 4; ++qt) {
    m[qt] = fmaxf(m[qt], __shfl_xor(m[qt], 16));
    m[qt] = fmaxf(m[qt], __shfl_xor(m[qt], 32));
  }
  if (lane < 16) {
#pragma unroll
    for (int qt = 0; qt < 4; ++qt) lbuf[w][qt * 16 + lane] = m[qt];
  }
  __syncthreads();
#pragma unroll
  for (int qt = 0; qt < 4; ++qt) {
    float mm = lbuf[0][qt * 16 + r15];
#pragma unroll
    for (int ww = 1; ww < 16; ++ww) mm = fmaxf(mm, lbuf[ww][qt * 16 + r15]);
    m[qt] = mm;
  }
  __syncthreads();
}

__device__ __forceinline__ void s_phase(
    unsigned char* __restrict__ P, int pbuf, const v8s kf, const v8s qf[4],
    const float m[4], int w, int lane, float lsum[4]) {
  const v4f vzero4 = {0.f, 0.f, 0.f, 0.f};
  const int quad = lane >> 4, r15 = lane & 15;
  unsigned char* pw = P + pbuf * 8704 + w * 16 + quad * 4;
#pragma unroll
  for (int qt = 0; qt < 4; ++qt) {
    v4f st = __builtin_amdgcn_mfma_f32_16x16x32_bf16(kf, qf[qt], vzero4, 0, 0, 0);
    float e0 = exp2_(st[0] - m[qt]), e1 = exp2_(st[1] - m[qt]);
    float e2 = exp2_(st[2] - m[qt]), e3 = exp2_(st[3] - m[qt]);
    lsum[qt] += (e0 + e1) + (e2 + e3);
    *(unsigned int*)(pw + (size_t)(qt * 16 + r15) * 136) = pack4_fp8(e0, e1, e2, e3);
  }
}

__device__ __forceinline__ void attn_loop(
    const unsigned short* __restrict__ Kp, const unsigned char* __restrict__ Vp,
    unsigned char* __restrict__ P, const v8s qf[4], const float m[4], int w, int lane,
    v16f acc[2], float lsum[4]) {
  if (w < 8) {
    // ---- S producer ----
    const unsigned short* Kl = Kp + (size_t)w * 512 + lane * 8;
    v8s kA = *(const v8s*)(Kl);
    v8s kB = *(const v8s*)(Kl + 4096);
    s_phase(P, 0, kA, qf, m, w, lane, lsum);
    barrier_lds();
#pragma unroll 2
    for (int t = 0; t < 32; ++t) {
      v8s kC = *(const v8s*)(Kl + (size_t)((t + 2) & 31) * 4096);
      if (t < 31) s_phase(P, (t + 1) & 1, kB, qf, m, w, lane, lsum);
      kA = kB;
      kB = kC;
      barrier_lds();
    }
  } else {
    // ---- PV consumer ----
    const int l31 = lane & 31, lh = lane >> 5;
    const unsigned char* Vl = Vp + (size_t)(w - 8) * 512 + lane * 8;
    u64 vA[8], vB[8];
#pragma unroll
    for (int s = 0; s < 8; ++s) vA[s] = *(const u64*)(Vl + (size_t)s * 4096);
    barrier_lds();
#pragma unroll 2
    for (int t = 0; t < 32; ++t) {
      // prefetch next tile's V (in flight across the barrier)
#pragma unroll
      for (int s = 0; s < 8; ++s)
        vB[s] = *(const u64*)(Vl + (size_t)((t + 1) & 31) * 32768 + s * 4096);
      const unsigned char* pb = P + (t & 1) * 8704;
#pragma unroll
      for (int s = 0; s < 8; ++s) {
        long pf0 = (long)*(const u64*)(pb + (size_t)l31 * 136 + s * 16 + lh * 8);
        long pf1 = (long)*(const u64*)(pb + (size_t)(32 + l31) * 136 + s * 16 + lh * 8);
        acc[0] = __builtin_amdgcn_mfma_f32_32x32x16_fp8_fp8((long)vA[s], pf0, acc[0], 0, 0, 0);
        acc[1] = __builtin_amdgcn_mfma_f32_32x32x16_fp8_fp8((long)vA[s], pf1, acc[1], 0, 0, 0);
      }
#pragma unroll
      for (int s = 0; s < 8; ++s) vA[s] = vB[s];
      barrier_lds();
    }
  }
}

// ---------------- single cooperative mega-kernel ----------------
// grid 256 x 1024 thr (1 block/CU, co-resident by cooperative launch).
// Phase A: weight convert (blocks 0-19). grid.sync.
// Phase B: prep for (b=blk&3, n0=(blk>>2)*64); 3 sources across wave-groups;
//          writes Q1/K1/K2/V1/V2 for the SAME batch this block attends.
// Phase C: producer/consumer attention (round-5 structure, 93.5us standalone).
__global__ __launch_bounds__(1024) void mega_kernel(
    const float* __restrict__ x, const float* __restrict__ y, const float* __restrict__ z,
    const float* __restrict__ q1w, const float* __restrict__ q1b,
    const float* __restrict__ k1w, const float* __restrict__ k1b,
    const float* __restrict__ v1w, const float* __restrict__ v1b,
    const float* __restrict__ g1p,
    const float* __restrict__ q2w, const float* __restrict__ q2b,
    const float* __restrict__ k2w, const float* __restrict__ k2b,
    const float* __restrict__ v2w, const float* __restrict__ v2b,
    const float* __restrict__ g2p,
    unsigned short* __restrict__ Wbf, unsigned short* __restrict__ Q1,
    unsigned short* __restrict__ K1, unsigned short* __restrict__ K2,
    unsigned char* __restrict__ V1, unsigned char* __restrict__ V2,
    float* __restrict__ outp) {
  __shared__ __align__(16) char smem[125952];  // phase B: 3x41984; phase C: 59392
  const int tid = threadIdx.x;
  const int b = blockIdx.x & 3;
  const int n0 = (blockIdx.x >> 2) * 64;
  cooperative_groups::grid_group grid = cooperative_groups::this_grid();

  // ================= phase A: weight convert+frag-pack =================
  {
    const int s = blockIdx.x * 1024 + tid;  // v8s slot, 20480 total
    if (s < 20480) {
      const float* src;
      int o, ch0;
      size_t obase;
      float scale = 1.0f;
      if (s < 3072) {
        const int wsel = s >> 10, r = s & 1023;
        src = wsel == 0 ? q1w : (wsel == 1 ? k1w : k2w);
        const int ot = r >> 9, cb = (r >> 6) & 7, lane = r & 63;
        o = ot * 16 + (lane & 15);
        ch0 = cb * 32 + ((lane >> 4) & 3) * 8;
        obase = (size_t)wsel * 8192 + (size_t)r * 8;
      } else if (s < 19456) {
        const int s2 = s - 3072, which = s2 >> 13, r = s2 & 8191;
        src = which == 0 ? v1w : v2w;
        const int ot = r >> 9, cb = (r >> 6) & 7, lane = r & 63;
        o = ot * 16 + (lane & 15);
        ch0 = cb * 32 + ((lane >> 4) & 3) * 8;
        obase = 32768 + (size_t)which * 65536 + (size_t)r * 8;
      } else {
        const int r = s - 19456;
        src = q2w;
        const int lane = r & 63;
        o = lane & 31;
        ch0 = (r >> 6) * 16 + (lane >> 5) * 8;
        obase = 24576 + (size_t)r * 8;
        scale = LOG2E;
      }
#pragma unroll
      for (int j = 0; j < 8; ++j)
        Wbf[obase + j] = f2bf(src[o * CDIM + ch0 + j] * scale);
    }
  }
  __threadfence();
  grid.sync();

  // ================= phase B: prep (transpose + Q/K/V projections) =================
  {
    const int src = tid >> 8;   // 0..3 (3 idles)
    const int ptid = tid & 255;
    const int lane = ptid & 63, wp = ptid >> 6;
    const int quad = lane >> 4, r15 = lane & 15, l31 = lane & 31, lh = lane >> 5;
    unsigned short (*t)[72] = (unsigned short (*)[72])(smem + (src < 3 ? src : 0) * 41984);
    unsigned short (*Kt)[40] = (unsigned short (*)[40])(smem + (src < 3 ? src : 0) * 41984 + 36864);
    if (src < 3) {
      const float* in = src == 0 ? x : (src == 1 ? y : z);
      const float* ip = in + (size_t)(b * CDIM) * NSEQ + n0;
      const int chb = ptid >> 4, c4 = (ptid & 15) * 4;
#pragma unroll
      for (int p = 0; p < 16; ++p) {
        const int ch = p * 16 + chb;
        float4 v = *(const float4*)(ip + (size_t)ch * NSEQ + c4);
        uint2 pk;
        pk.x = pack_bf16(v.x, v.y);
        pk.y = pack_bf16(v.z, v.w);
        *(uint2*)&t[ch][c4] = pk;
      }
    }
    __syncthreads();
    v8s af[8];
    if (src < 3) {
#pragma unroll
      for (int cb = 0; cb < 8; ++cb) {
        union { unsigned short e[8]; v8s v; } u;
#pragma unroll
        for (int j = 0; j < 8; ++j) u.e[j] = t[cb * 32 + quad * 8 + j][wp * 16 + r15];
        af[cb] = u.v;
      }
    }
    __syncthreads();  // t region free (all gathers done) -> reusable as Vt8
    if (src < 3) {
      const int nt = (blockIdx.x >> 2) * 4 + wp;
      const unsigned short* Wqk = Wbf + src * 8192;
      v4f a0 = {0.f, 0.f, 0.f, 0.f}, a1 = a0;
#pragma unroll
      for (int cb = 0; cb < 8; ++cb) {
        v8s b0 = *(const v8s*)(Wqk + (size_t)cb * 512 + lane * 8);
        v8s b1 = *(const v8s*)(Wqk + (size_t)(8 + cb) * 512 + lane * 8);
        a0 = __builtin_amdgcn_mfma_f32_16x16x32_bf16(af[cb], b0, a0, 0, 0, 0);
        a1 = __builtin_amdgcn_mfma_f32_16x16x32_bf16(af[cb], b1, a1, 0, 0, 0);
      }
      if (src == 0) {
#pragma unroll
        for (int r = 0; r < 4; ++r) {
          Q1[((size_t)b * NSEQ + nt * 16 + quad * 4 + r) * CQKD + r15] =
              f2bf((a0[r] + q1b[r15]) * LOG2E);
          Q1[((size_t)b * NSEQ + nt * 16 + quad * 4 + r) * CQKD + 16 + r15] =
              f2bf((a1[r] + q1b[16 + r15]) * LOG2E);
        }
      } else {
        const float* kbias = src == 1 ? k1b : k2b;
#pragma unroll
        for (int r = 0; r < 4; ++r) {
          Kt[wp * 16 + quad * 4 + r][r15] = f2bf(a0[r] + kbias[r15]);
          Kt[wp * 16 + quad * 4 + r][16 + r15] = f2bf(a1[r] + kbias[16 + r15]);
        }
        const unsigned short* Wv = Wbf + 32768 + (src - 1) * 65536;
        const float* vbias = src == 1 ? v1b : v2b;
        unsigned char* Vt8 = (unsigned char*)t;
        // V projection in two 8-slab halves (keeps VGPR under the 1024-thr cap)
#pragma unroll 1
        for (int half = 0; half < 2; ++half) {
          v4f vacc[8];
#pragma unroll
          for (int o2 = 0; o2 < 8; ++o2) vacc[o2] = (v4f){0.f, 0.f, 0.f, 0.f};
#pragma unroll
          for (int cb = 0; cb < 8; ++cb) {
            const v8s afc = af[cb];
#pragma unroll
            for (int o2 = 0; o2 < 8; ++o2) {
              v8s bfr = *(const v8s*)(Wv + (size_t)((half * 8 + o2) * 8 + cb) * 512 + lane * 8);
              vacc[o2] = __builtin_amdgcn_mfma_f32_16x16x32_bf16(afc, bfr, vacc[o2], 0, 0, 0);
            }
          }
#pragma unroll
          for (int o2 = 0; o2 < 8; ++o2) {
            const int ch = (half * 8 + o2) * 16 + r15;
            const float bv = vbias[ch];
            *(unsigned int*)&Vt8[(size_t)ch * 72 + wp * 16 + quad * 4] =
                pack4_fp8(vacc[o2][0] + bv, vacc[o2][1] + bv, vacc[o2][2] + bv, vacc[o2][3] + bv);
          }
        }
        unsigned short* Kout = (src == 1 ? K1 : K2) + (size_t)b * (NSEQ / 16) * 512;
        *(v8s*)(Kout + ((size_t)nt * 64 + lane) * 8) = *(const v8s*)&Kt[wp * 16 + r15][quad * 8];
      }
    }
    __syncthreads();  // Vt8 complete
    if (src == 1 || src == 2) {
      const int nt = (blockIdx.x >> 2) * 4 + wp;
      unsigned char* Vt8 = (unsigned char*)t;
      unsigned char* Vout = (src == 1 ? V1 : V2) + (size_t)b * (NSEQ / 16) * 8 * 512;
#pragma unroll
      for (int chb = 0; chb < 8; ++chb)
        *(u64*)(Vout + (((size_t)nt * 8 + chb) * 64 + lane) * 8) =
            *(const u64*)&Vt8[(size_t)(chb * 32 + l31) * 72 + wp * 16 + lh * 8];
    }
  }
  __threadfence();
  grid.sync();

  // ================= phase C: fused double attention =================
  {
    unsigned char* P = (unsigned char*)smem;                       // 17408 B
    unsigned short* out1T = (unsigned short*)(smem + 17408);       // 33792 B
    unsigned short* q2s = (unsigned short*)(smem + 51200);         // 4096 B
    float (*lbuf)[64] = (float (*)[64])(smem + 55296);             // 4096 B

    const int lane = tid & 63;
    const int w = tid >> 6;        // 0..15; 0-7 = S producers, 8-15 = PV consumers
    const int quad = lane >> 4;
    const int r15 = lane & 15;
    const int l31 = lane & 31, lh = lane >> 5;

    const float g1 = g1p[0];
    const float g2 = g2p[0];

    const unsigned short* Qp  = Q1 + (size_t)b * NSEQ * CQKD;
    const unsigned short* K1p = K1 + (size_t)b * (NSEQ / 16) * 512;
    const unsigned short* K2p = K2 + (size_t)b * (NSEQ / 16) * 512;
    const unsigned char* V1p  = V1 + (size_t)b * (NSEQ / 16) * 8 * 512;
    const unsigned char* V2p  = V2 + (size_t)b * (NSEQ / 16) * 8 * 512;
    const unsigned short* W2g = Wbf + 24576;

    v8s qf[4];
#pragma unroll
    for (int qt = 0; qt < 4; ++qt)
      qf[qt] = *(const v8s*)(Qp + (n0 + qt * 16 + r15) * CQKD + quad * 8);

    v16f acc[2];
    float lsum[4] = {0.f, 0.f, 0.f, 0.f};
    float m[4];
    acc[0] = (v16f)(0.f); acc[1] = (v16f)(0.f);

    // ---- layer 1 ----
    max_pass16(K1p, qf, w, lane, lbuf, m);
    attn_loop(K1p, V1p, P, qf, m, w, lane, acc, lsum);
    if (w < 8) {
#pragma unroll
      for (int qt = 0; qt < 4; ++qt) {
        lsum[qt] += __shfl_xor(lsum[qt], 16);
        lsum[qt] += __shfl_xor(lsum[qt], 32);
      }
      if (lane < 16) {
#pragma unroll
        for (int qt = 0; qt < 4; ++qt) lbuf[w][qt * 16 + lane] = lsum[qt];
      }
    }
    __syncthreads();
    float rinv[2];
#pragma unroll
    for (int qh = 0; qh < 2; ++qh) {
      const int q = qh * 32 + l31;
      float d = 0.f;
#pragma unroll
      for (int ww = 0; ww < 8; ++ww) d += lbuf[ww][q];
      rinv[qh] = 1.0f / d;
    }
    if (w >= 8) {  // layer-1 epilogue by PV waves (they hold acc)
      const int cw = (w - 8) * 32;
#pragma unroll
      for (int qh = 0; qh < 2; ++qh) {
        const int q = qh * 32 + l31;
#pragma unroll
        for (int rg = 0; rg < 4; ++rg) {
          const int c = cw + 8 * rg + 4 * lh;
          float o0 = g1 * (acc[qh][rg * 4 + 0] * rinv[qh]) + x[((size_t)b * CDIM + c + 0) * NSEQ + n0 + q];
          float o1 = g1 * (acc[qh][rg * 4 + 1] * rinv[qh]) + x[((size_t)b * CDIM + c + 1) * NSEQ + n0 + q];
          float o2 = g1 * (acc[qh][rg * 4 + 2] * rinv[qh]) + x[((size_t)b * CDIM + c + 2) * NSEQ + n0 + q];
          float o3 = g1 * (acc[qh][rg * 4 + 3] * rinv[qh]) + x[((size_t)b * CDIM + c + 3) * NSEQ + n0 + q];
          uint2 pk;
          pk.x = pack_bf16(o0, o1);
          pk.y = pack_bf16(o2, o3);
          *(uint2*)(out1T + (size_t)q * 264 + c) = pk;
        }
      }
    }
    __syncthreads();

    // ---- q2 projection (waves 0,1) ----
    if (w < 2) {
      const int qh = w;
      v16f qacc = (v16f)(0.f);
#pragma unroll
      for (int s = 0; s < 16; ++s) {
        v8s af = *(const v8s*)(W2g + (size_t)(s * 64 + lane) * 8);
        v8s bfr = *(const v8s*)(out1T + (size_t)(qh * 32 + l31) * 264 + s * 16 + lh * 8);
        qacc = __builtin_amdgcn_mfma_f32_32x32x16_bf16(af, bfr, qacc, 0, 0, 0);
      }
#pragma unroll
      for (int rg = 0; rg < 4; ++rg) {
        const int o = 8 * rg + 4 * lh;
        uint2 pk;
        pk.x = pack_bf16(qacc[rg * 4 + 0] + q2b[o + 0] * LOG2E, qacc[rg * 4 + 1] + q2b[o + 1] * LOG2E);
        pk.y = pack_bf16(qacc[rg * 4 + 2] + q2b[o + 2] * LOG2E, qacc[rg * 4 + 3] + q2b[o + 3] * LOG2E);
        *(uint2*)(q2s + (size_t)(qh * 32 + l31) * 32 + o) = pk;
      }
    }
    __syncthreads();

    // ---- layer 2 ----
#pragma unroll
    for (int qt = 0; qt < 4; ++qt)
      qf[qt] = *(const v8s*)(q2s + (qt * 16 + r15) * 32 + quad * 8);
    acc[0] = (v16f)(0.f); acc[1] = (v16f)(0.f);
#pragma unroll
    for (int qt = 0; qt < 4; ++qt) lsum[qt] = 0.f;
    max_pass16(K2p, qf, w, lane, lbuf, m);
    attn_loop(K2p, V2p, P, qf, m, w, lane, acc, lsum);
    if (w < 8) {
#pragma unroll
      for (int qt = 0; qt < 4; ++qt) {
        lsum[qt] += __shfl_xor(lsum[qt], 16);
        lsum[qt] += __shfl_xor(lsum[qt], 32);
      }
      if (lane < 16) {
#pragma unroll
        for (int qt = 0; qt < 4; ++qt) lbuf[w][qt * 16 + lane] = lsum[qt];
      }
    }
    __syncthreads();
#pragma unroll
    for (int qh = 0; qh < 2; ++qh) {
      const int q = qh * 32 + l31;
      float d = 0.f;
#pragma unroll
      for (int ww = 0; ww < 8; ++ww) d += lbuf[ww][q];
      rinv[qh] = 1.0f / d;
    }
    if (w >= 8) {  // layer-2 epilogue by PV waves
      const int cw = (w - 8) * 32;
#pragma unroll
      for (int qh = 0; qh < 2; ++qh) {
        const int q = qh * 32 + l31;
#pragma unroll
        for (int rg = 0; rg < 4; ++rg) {
          const int c = cw + 8 * rg + 4 * lh;
#pragma unroll
          for (int i = 0; i < 4; ++i) {
            float res = bf2f(out1T[(size_t)q * 264 + c + i]);
            outp[((size_t)b * CDIM + c + i) * NSEQ + n0 + q] =
                g2 * (acc[qh][rg * 4 + i] * rinv[qh]) + res;
          }
        }
      }
    }
  }
}

extern "C" void kernel_launch(void* const* d_in, const int* in_sizes, int n_in,
                              void* d_out, int out_size, void* d_ws, size_t ws_size,
                              hipStream_t stream) {
  const float* x   = (const float*)d_in[0];
  const float* y   = (const float*)d_in[1];
  const float* z   = (const float*)d_in[2];
  const float* q1w = (const float*)d_in[3];
  const float* q1b = (const float*)d_in[4];
  const float* k1w = (const float*)d_in[5];
  const float* k1b = (const float*)d_in[6];
  const float* v1w = (const float*)d_in[7];
  const float* v1b = (const float*)d_in[8];
  const float* g1  = (const float*)d_in[9];
  const float* q2w = (const float*)d_in[10];
  const float* q2b = (const float*)d_in[11];
  const float* k2w = (const float*)d_in[12];
  const float* k2b = (const float*)d_in[13];
  const float* v2w = (const float*)d_in[14];
  const float* v2b = (const float*)d_in[15];
  const float* g2  = (const float*)d_in[16];
  char* ws = (char*)d_ws;
  unsigned short* Wbf = (unsigned short*)(ws);             // 327,680 B
  unsigned short* Q1  = (unsigned short*)(ws + 327680);    // 1 MB
  unsigned short* K1  = (unsigned short*)(ws + 1376256);   // 1 MB
  unsigned short* K2  = (unsigned short*)(ws + 2424832);   // 1 MB
  unsigned char*  V1  = (unsigned char*)(ws + 3473408);    // 4 MB (fp8)
  unsigned char*  V2  = (unsigned char*)(ws + 7667712);    // 4 MB (fp8) -> 11.9 MB total
  float* outp = (float*)d_out;

  void* args[] = {(void*)&x,   (void*)&y,   (void*)&z,   (void*)&q1w, (void*)&q1b,
                  (void*)&k1w, (void*)&k1b, (void*)&v1w, (void*)&v1b, (void*)&g1,
                  (void*)&q2w, (void*)&q2b, (void*)&k2w, (void*)&k2b, (void*)&v2w,
                  (void*)&v2b, (void*)&g2,  (void*)&Wbf, (void*)&Q1,  (void*)&K1,
                  (void*)&K2,  (void*)&V1,  (void*)&V2,  (void*)&outp};
  hipLaunchCooperativeKernel((const void*)mega_kernel, dim3(256), dim3(1024), args, 0,
                             stream);
}

// Round 7
// 210.857 us; speedup vs baseline: 2.2329x; 2.2329x over previous
//
#include <hip/hip_runtime.h>
#include <hip/hip_bf16.h>

#define NSEQ 4096
#define CDIM 256
#define CQKD 32
#define LOG2E 1.4426950408889634f

typedef float v4f __attribute__((ext_vector_type(4)));
typedef float v16f __attribute__((ext_vector_type(16)));
typedef short v8s __attribute__((ext_vector_type(8)));
typedef unsigned long long u64;

__device__ __forceinline__ float exp2_(float x) {
#if __has_builtin(__builtin_amdgcn_exp2f)
  return __builtin_amdgcn_exp2f(x);
#else
  float r;
  __asm__("v_exp_f32 %0, %1" : "=v"(r) : "v"(x));
  return r;
#endif
}

__device__ __forceinline__ unsigned short f2bf(float x) {
  unsigned u = __builtin_bit_cast(unsigned, x);
  unsigned r = (u + 0x7FFFu + ((u >> 16) & 1u)) >> 16;
  return (unsigned short)r;
}
__device__ __forceinline__ float bf2f(unsigned short s) {
  unsigned u = ((unsigned)s) << 16;
  return __builtin_bit_cast(float, u);
}
__device__ __forceinline__ unsigned int pack_bf16(float a, float b) {
#if __has_builtin(__builtin_amdgcn_cvt_pk_bf16_f32)
  typedef __bf16 v2bf __attribute__((ext_vector_type(2)));
  v2bf r = __builtin_amdgcn_cvt_pk_bf16_f32(a, b);
  return __builtin_bit_cast(unsigned int, r);
#else
  return ((unsigned)f2bf(b) << 16) | (unsigned)f2bf(a);
#endif
}

// fp8 e4m3fn (OCP) encode, software fallback
__device__ __forceinline__ unsigned char f2e4m3(float x) {
  unsigned u = __builtin_bit_cast(unsigned, x);
  unsigned s = (u >> 24) & 0x80u;
  unsigned au = u & 0x7fffffffu;
  if (au > 0x43e00000u) return (unsigned char)(s | 0x7eu);  // clamp to 448
  if (au < 0x3c800000u) {                                   // subnormal range (<2^-6)
    float ax = __builtin_bit_cast(float, au);
    int q = (int)(ax * 512.0f + 0.5f);
    if (q > 7) q = 7;
    return (unsigned char)(s | (unsigned)q);
  }
  int e = (int)((au >> 23) & 0xffu) - 127 + 7;
  unsigned m = au & 0x7fffffu;
  unsigned mr = m + 0x7ffffu + ((m >> 20) & 1u);
  if (mr >= 0x800000u) { mr -= 0x800000u; e += 1; if (e >= 16) return (unsigned char)(s | 0x7e); }
  return (unsigned char)(s | ((unsigned)e << 3) | (mr >> 20));
}
__device__ __forceinline__ unsigned int pack4_fp8(float a, float b, float c, float d) {
#if __has_builtin(__builtin_amdgcn_cvt_pk_fp8_f32)
  int v = 0;
  v = __builtin_amdgcn_cvt_pk_fp8_f32(a, b, v, false);
  v = __builtin_amdgcn_cvt_pk_fp8_f32(c, d, v, true);
  return (unsigned int)v;
#else
  return (unsigned)f2e4m3(a) | ((unsigned)f2e4m3(b) << 8) |
         ((unsigned)f2e4m3(c) << 16) | ((unsigned)f2e4m3(d) << 24);
#endif
}

// LDS-only split barrier (orders LDS producer->consumer without draining vmcnt)
__device__ __forceinline__ void barrier_lds() {
  __asm__ __volatile__("s_waitcnt lgkmcnt(0)\n\ts_barrier" ::: "memory");
}

// ---------------- weight convert+frag-pack (bf16) ----------------
__global__ __launch_bounds__(256) void convw_kernel(
    const float* __restrict__ q1w, const float* __restrict__ k1w,
    const float* __restrict__ k2w, const float* __restrict__ q2w,
    const float* __restrict__ v1w, const float* __restrict__ v2w,
    unsigned short* __restrict__ W) {
  const int s = blockIdx.x * 256 + threadIdx.x;  // v8s slot, 20480 total
  const float* src;
  int o, ch0;
  size_t obase;
  float scale = 1.0f;
  if (s < 3072) {
    const int wsel = s >> 10, r = s & 1023;
    src = wsel == 0 ? q1w : (wsel == 1 ? k1w : k2w);
    const int ot = r >> 9, cb = (r >> 6) & 7, lane = r & 63;
    o = ot * 16 + (lane & 15);
    ch0 = cb * 32 + ((lane >> 4) & 3) * 8;
    obase = (size_t)wsel * 8192 + (size_t)r * 8;
  } else if (s < 19456) {
    const int s2 = s - 3072, which = s2 >> 13, r = s2 & 8191;
    src = which == 0 ? v1w : v2w;
    const int ot = r >> 9, cb = (r >> 6) & 7, lane = r & 63;
    o = ot * 16 + (lane & 15);
    ch0 = cb * 32 + ((lane >> 4) & 3) * 8;
    obase = 32768 + (size_t)which * 65536 + (size_t)r * 8;
  } else {
    const int r = s - 19456;
    src = q2w;
    const int lane = r & 63;
    o = lane & 31;
    ch0 = (r >> 6) * 16 + (lane >> 5) * 8;
    obase = 24576 + (size_t)r * 8;
    scale = LOG2E;
  }
#pragma unroll
  for (int j = 0; j < 8; ++j)
    W[obase + j] = f2bf(src[o * CDIM + ch0 + j] * scale);
}

// ---------------- prep: transpose + Q/K/V projections (V emitted fp8) ----------------
__global__ __launch_bounds__(256) void prep_kernel(
    const float* __restrict__ x, const float* __restrict__ y,
    const float* __restrict__ z, const unsigned short* __restrict__ Wbf,
    const float* __restrict__ q1b, const float* __restrict__ k1b,
    const float* __restrict__ k2b, const float* __restrict__ v1b,
    const float* __restrict__ v2b, unsigned short* __restrict__ Q1,
    unsigned short* __restrict__ K1, unsigned short* __restrict__ K2,
    unsigned char* __restrict__ V1, unsigned char* __restrict__ V2) {
  __shared__ unsigned short t[256][72];  // staging [ch][n] bf16; reused as fp8 Vt
  __shared__ unsigned short Kt[64][40];
  const int src = blockIdx.z;
  const float* in = src == 0 ? x : (src == 1 ? y : z);
  const int b = blockIdx.y;
  const int n0 = blockIdx.x * 64;
  const int tid = threadIdx.x, lane = tid & 63, w = tid >> 6;
  const int quad = lane >> 4, r15 = lane & 15, l31 = lane & 31, lh = lane >> 5;
  const float* ip = in + (size_t)(b * CDIM) * NSEQ + n0;
  {
    const int chb = tid >> 4, c4 = (tid & 15) * 4;
#pragma unroll
    for (int p = 0; p < 16; ++p) {
      const int ch = p * 16 + chb;
      float4 v = *(const float4*)(ip + (size_t)ch * NSEQ + c4);
      uint2 pk;
      pk.x = pack_bf16(v.x, v.y);
      pk.y = pack_bf16(v.z, v.w);
      *(uint2*)&t[ch][c4] = pk;
    }
  }
  __syncthreads();
  v8s af[8];
#pragma unroll
  for (int cb = 0; cb < 8; ++cb) {
    union { unsigned short e[8]; v8s v; } u;
#pragma unroll
    for (int j = 0; j < 8; ++j) u.e[j] = t[cb * 32 + quad * 8 + j][w * 16 + r15];
    af[cb] = u.v;
  }
  const int nt = blockIdx.x * 4 + w;
  const unsigned short* Wqk = Wbf + src * 8192;
  v4f a0 = {0.f, 0.f, 0.f, 0.f}, a1 = a0;
#pragma unroll
  for (int cb = 0; cb < 8; ++cb) {
    v8s b0 = *(const v8s*)(Wqk + (size_t)cb * 512 + lane * 8);
    v8s b1 = *(const v8s*)(Wqk + (size_t)(8 + cb) * 512 + lane * 8);
    a0 = __builtin_amdgcn_mfma_f32_16x16x32_bf16(af[cb], b0, a0, 0, 0, 0);
    a1 = __builtin_amdgcn_mfma_f32_16x16x32_bf16(af[cb], b1, a1, 0, 0, 0);
  }
  if (src == 0) {
#pragma unroll
    for (int r = 0; r < 4; ++r) {
      Q1[((size_t)b * NSEQ + nt * 16 + quad * 4 + r) * CQKD + r15] =
          f2bf((a0[r] + q1b[r15]) * LOG2E);
      Q1[((size_t)b * NSEQ + nt * 16 + quad * 4 + r) * CQKD + 16 + r15] =
          f2bf((a1[r] + q1b[16 + r15]) * LOG2E);
    }
    return;
  }
  const float* kbias = src == 1 ? k1b : k2b;
#pragma unroll
  for (int r = 0; r < 4; ++r) {
    Kt[w * 16 + quad * 4 + r][r15] = f2bf(a0[r] + kbias[r15]);
    Kt[w * 16 + quad * 4 + r][16 + r15] = f2bf(a1[r] + kbias[16 + r15]);
  }
  const unsigned short* Wv = Wbf + 32768 + (src - 1) * 65536;
  const float* vbias = src == 1 ? v1b : v2b;
  v4f vacc[16];
#pragma unroll
  for (int ot = 0; ot < 16; ++ot) vacc[ot] = (v4f){0.f, 0.f, 0.f, 0.f};
#pragma unroll
  for (int cb = 0; cb < 8; ++cb) {
    const v8s afc = af[cb];
#pragma unroll
    for (int ot = 0; ot < 16; ++ot) {
      v8s bf = *(const v8s*)(Wv + (size_t)(ot * 8 + cb) * 512 + lane * 8);
      vacc[ot] = __builtin_amdgcn_mfma_f32_16x16x32_bf16(afc, bf, vacc[ot], 0, 0, 0);
    }
  }
  __syncthreads();  // staging reads done -> reuse t as fp8 Vt (rows 72 B)
  unsigned char* Vt8 = (unsigned char*)t;
#pragma unroll
  for (int ot = 0; ot < 16; ++ot) {
    const int ch = ot * 16 + r15;
    const float bv = vbias[ch];
    *(unsigned int*)&Vt8[(size_t)ch * 72 + w * 16 + quad * 4] =
        pack4_fp8(vacc[ot][0] + bv, vacc[ot][1] + bv, vacc[ot][2] + bv, vacc[ot][3] + bv);
  }
  {
    unsigned short* Kout = (src == 1 ? K1 : K2) + (size_t)b * (NSEQ / 16) * 512;
    *(v8s*)(Kout + ((size_t)nt * 64 + lane) * 8) = *(const v8s*)&Kt[w * 16 + r15][quad * 8];
  }
  __syncthreads();  // Vt complete
  unsigned char* Vout = (src == 1 ? V1 : V2) + (size_t)b * (NSEQ / 16) * 8 * 512;
#pragma unroll
  for (int chb = 0; chb < 8; ++chb)
    *(u64*)(Vout + (((size_t)nt * 8 + chb) * 64 + lane) * 8) =
        *(const u64*)&Vt8[(size_t)(chb * 32 + l31) * 72 + w * 16 + lh * 8];
}

// ---------------- fused double attention: producer/consumer, tile-PAIR steps ----------------
// 1024 thr = 16 waves, 64 q/block, grid 256 (1 block/CU, 4 waves/SIMD).
// Waves 0-7: S-PRODUCERS — per step: 2 tiles (2 K loads, 8 S-MFMA, 32 exp2, packs,
//   8 P writes). Waves 8-15: PV-CONSUMERS — per step: 2 tiles (32 P reads, 32 fp8
//   MFMA w/ setprio(1), 16 V loads). P is a 4-deep ring (pair p -> bufs {2(p&1),
//   2(p&1)+1}); 17 barriers/layer (vs 33 single-tile) amortizes barrier skew.
// One lgkmcnt-only barrier per step (vmcnt stays in flight). Per-q global max
// from 16-wave max_pass keeps exp2(s-m) in (0,1] -> e4m3-safe.

__device__ __forceinline__ void max_pass16(
    const unsigned short* __restrict__ Kp, const v8s qf[4], int w, int lane,
    float (*lbuf)[64], float m[4]) {
  const v4f vzero4 = {0.f, 0.f, 0.f, 0.f};
  const int r15 = lane & 15;
  const unsigned short* Kl = Kp + (size_t)w * 512 + lane * 8;
  v8s kA = *(const v8s*)(Kl);
  v8s kB = *(const v8s*)(Kl + 8192);
#pragma unroll
  for (int qt = 0; qt < 4; ++qt) m[qt] = -3.0e38f;
#pragma unroll 2
  for (int kt = 0; kt < 16; ++kt) {
    v8s kC = *(const v8s*)(Kl + (size_t)((kt + 2) & 15) * 8192);  // depth-2 prefetch
#pragma unroll
    for (int qt = 0; qt < 4; ++qt) {
      v4f st = __builtin_amdgcn_mfma_f32_16x16x32_bf16(kA, qf[qt], vzero4, 0, 0, 0);
      m[qt] = fmaxf(m[qt], fmaxf(fmaxf(st[0], st[1]), fmaxf(st[2], st[3])));
    }
    kA = kB;
    kB = kC;
  }
#pragma unroll
  for (int qt = 0; qt < 4; ++qt) {
    m[qt] = fmaxf(m[qt], __shfl_xor(m[qt], 16));
    m[qt] = fmaxf(m[qt], __shfl_xor(m[qt], 32));
  }
  if (lane < 16) {
#pragma unroll
    for (int qt = 0; qt < 4; ++qt) lbuf[w][qt * 16 + lane] = m[qt];
  }
  __syncthreads();
#pragma unroll
  for (int qt = 0; qt < 4; ++qt) {
    float mm = lbuf[0][qt * 16 + r15];
#pragma unroll
    for (int ww = 1; ww < 16; ++ww) mm = fmaxf(mm, lbuf[ww][qt * 16 + r15]);
    m[qt] = mm;
  }
  __syncthreads();
}

__device__ __forceinline__ void s_phase(
    unsigned char* __restrict__ P, int pbuf, const v8s kf, const v8s qf[4],
    const float m[4], int w, int lane, float lsum[4]) {
  const v4f vzero4 = {0.f, 0.f, 0.f, 0.f};
  const int quad = lane >> 4, r15 = lane & 15;
  unsigned char* pw = P + pbuf * 8704 + w * 16 + quad * 4;
#pragma unroll
  for (int qt = 0; qt < 4; ++qt) {
    v4f st = __builtin_amdgcn_mfma_f32_16x16x32_bf16(kf, qf[qt], vzero4, 0, 0, 0);
    float e0 = exp2_(st[0] - m[qt]), e1 = exp2_(st[1] - m[qt]);
    float e2 = exp2_(st[2] - m[qt]), e3 = exp2_(st[3] - m[qt]);
    lsum[qt] += (e0 + e1) + (e2 + e3);
    *(unsigned int*)(pw + (size_t)(qt * 16 + r15) * 136) = pack4_fp8(e0, e1, e2, e3);
  }
}

__device__ __forceinline__ void pv_tile(
    const unsigned char* __restrict__ P, int pbuf, const u64 vf[8], int lane,
    v16f acc[2]) {
  const int l31 = lane & 31, lh = lane >> 5;
  const unsigned char* pb = P + pbuf * 8704;
  __builtin_amdgcn_s_setprio(1);
#pragma unroll
  for (int s = 0; s < 8; ++s) {
    long pf0 = (long)*(const u64*)(pb + (size_t)l31 * 136 + s * 16 + lh * 8);
    long pf1 = (long)*(const u64*)(pb + (size_t)(32 + l31) * 136 + s * 16 + lh * 8);
    acc[0] = __builtin_amdgcn_mfma_f32_32x32x16_fp8_fp8((long)vf[s], pf0, acc[0], 0, 0, 0);
    acc[1] = __builtin_amdgcn_mfma_f32_32x32x16_fp8_fp8((long)vf[s], pf1, acc[1], 0, 0, 0);
  }
  __builtin_amdgcn_s_setprio(0);
}

__device__ __forceinline__ void attn_loop(
    const unsigned short* __restrict__ Kp, const unsigned char* __restrict__ Vp,
    unsigned char* __restrict__ P, const v8s qf[4], const float m[4], int w, int lane,
    v16f acc[2], float lsum[4]) {
  if (w < 8) {
    // ---- S producer: 2 tiles per step ----
    const unsigned short* Kl = Kp + (size_t)w * 512 + lane * 8;
    v8s k0 = *(const v8s*)(Kl);
    v8s k1 = *(const v8s*)(Kl + 4096);
    // pair 0
    s_phase(P, 0, k0, qf, m, w, lane, lsum);
    k0 = *(const v8s*)(Kl + 2 * 4096);
    s_phase(P, 1, k1, qf, m, w, lane, lsum);
    k1 = *(const v8s*)(Kl + 3 * 4096);
    barrier_lds();  // B1
#pragma unroll 1
    for (int p = 1; p < 16; ++p) {
      const int bs = (p & 1) * 2;
      s_phase(P, bs, k0, qf, m, w, lane, lsum);
      k0 = *(const v8s*)(Kl + (size_t)((2 * p + 2) & 31) * 4096);
      s_phase(P, bs + 1, k1, qf, m, w, lane, lsum);
      k1 = *(const v8s*)(Kl + (size_t)((2 * p + 3) & 31) * 4096);
      barrier_lds();  // B(p+1)
    }
    barrier_lds();  // B17 (PV consumes pair 15)
  } else {
    // ---- PV consumer: 2 tiles per step ----
    const unsigned char* Vl = Vp + (size_t)(w - 8) * 512 + lane * 8;
    u64 v0[8], v1[8];
#pragma unroll
    for (int s = 0; s < 8; ++s) v0[s] = *(const u64*)(Vl + (size_t)s * 4096);
#pragma unroll
    for (int s = 0; s < 8; ++s) v1[s] = *(const u64*)(Vl + 32768 + (size_t)s * 4096);
    barrier_lds();  // B1
#pragma unroll 1
    for (int p = 0; p < 15; ++p) {
      const int bs = (p & 1) * 2;
      pv_tile(P, bs, v0, lane, acc);  // tile 2p
      // prefetch V(2p+2) into v0 (issued after v0's MFMA operands are read)
#pragma unroll
      for (int s = 0; s < 8; ++s)
        v0[s] = *(const u64*)(Vl + (size_t)(2 * p + 2) * 32768 + s * 4096);
      pv_tile(P, bs + 1, v1, lane, acc);  // tile 2p+1
#pragma unroll
      for (int s = 0; s < 8; ++s)
        v1[s] = *(const u64*)(Vl + (size_t)(2 * p + 3) * 32768 + s * 4096);
      barrier_lds();  // B(p+2)
    }
    // pair 15 (bufs 2,3)
    pv_tile(P, 2, v0, lane, acc);
    pv_tile(P, 3, v1, lane, acc);
    barrier_lds();  // B17
  }
}

__global__ __launch_bounds__(1024, 4) void fused_attn_kernel(
    const unsigned short* __restrict__ Q1g, const unsigned short* __restrict__ K1g,
    const unsigned char* __restrict__ V1g, const unsigned short* __restrict__ K2g,
    const unsigned char* __restrict__ V2g, const unsigned short* __restrict__ W2g,
    const float* __restrict__ x, const float* __restrict__ q2b,
    const float* __restrict__ g1p, const float* __restrict__ g2p,
    float* __restrict__ outp) {
  __shared__ __align__(16) unsigned char P[4 * 8704];        // 34 KB fp8 P ring
  __shared__ __align__(16) unsigned short out1T[64 * 264];   // 33.8 KB [q][c] bf16
  __shared__ __align__(16) unsigned short q2s[64 * 32];      // 4 KB [q][o]
  __shared__ float lbuf[16][64];                             // 4 KB

  const int tid = threadIdx.x;
  const int lane = tid & 63;
  const int w = tid >> 6;        // 0..15; 0-7 = S producers, 8-15 = PV consumers
  const int quad = lane >> 4;
  const int r15 = lane & 15;
  const int l31 = lane & 31, lh = lane >> 5;
  const int b = blockIdx.x & 3;
  const int n0 = (blockIdx.x >> 2) * 64;

  const float g1 = g1p[0];
  const float g2 = g2p[0];

  const unsigned short* Qp  = Q1g + (size_t)b * NSEQ * CQKD;
  const unsigned short* K1p = K1g + (size_t)b * (NSEQ / 16) * 512;
  const unsigned short* K2p = K2g + (size_t)b * (NSEQ / 16) * 512;
  const unsigned char* V1p  = V1g + (size_t)b * (NSEQ / 16) * 8 * 512;
  const unsigned char* V2p  = V2g + (size_t)b * (NSEQ / 16) * 8 * 512;

  v8s qf[4];
#pragma unroll
  for (int qt = 0; qt < 4; ++qt)
    qf[qt] = *(const v8s*)(Qp + (n0 + qt * 16 + r15) * CQKD + quad * 8);

  v16f acc[2];
  float lsum[4] = {0.f, 0.f, 0.f, 0.f};
  float m[4];
  acc[0] = (v16f)(0.f); acc[1] = (v16f)(0.f);

  // ---- layer 1 ----
  max_pass16(K1p, qf, w, lane, lbuf, m);
  attn_loop(K1p, V1p, P, qf, m, w, lane, acc, lsum);
  // lsum reduce: S-waves only hold it
  if (w < 8) {
#pragma unroll
    for (int qt = 0; qt < 4; ++qt) {
      lsum[qt] += __shfl_xor(lsum[qt], 16);
      lsum[qt] += __shfl_xor(lsum[qt], 32);
    }
    if (lane < 16) {
#pragma unroll
      for (int qt = 0; qt < 4; ++qt) lbuf[w][qt * 16 + lane] = lsum[qt];
    }
  }
  __syncthreads();
  float rinv[2];
#pragma unroll
  for (int qh = 0; qh < 2; ++qh) {
    const int q = qh * 32 + l31;
    float d = 0.f;
#pragma unroll
    for (int ww = 0; ww < 8; ++ww) d += lbuf[ww][q];
    rinv[qh] = 1.0f / d;
  }
  if (w >= 8) {  // layer-1 epilogue by PV waves (they hold acc)
    const int cw = (w - 8) * 32;
#pragma unroll
    for (int qh = 0; qh < 2; ++qh) {
      const int q = qh * 32 + l31;
#pragma unroll
      for (int rg = 0; rg < 4; ++rg) {
        const int c = cw + 8 * rg + 4 * lh;
        float o0 = g1 * (acc[qh][rg * 4 + 0] * rinv[qh]) + x[((size_t)b * CDIM + c + 0) * NSEQ + n0 + q];
        float o1 = g1 * (acc[qh][rg * 4 + 1] * rinv[qh]) + x[((size_t)b * CDIM + c + 1) * NSEQ + n0 + q];
        float o2 = g1 * (acc[qh][rg * 4 + 2] * rinv[qh]) + x[((size_t)b * CDIM + c + 2) * NSEQ + n0 + q];
        float o3 = g1 * (acc[qh][rg * 4 + 3] * rinv[qh]) + x[((size_t)b * CDIM + c + 3) * NSEQ + n0 + q];
        uint2 pk;
        pk.x = pack_bf16(o0, o1);
        pk.y = pack_bf16(o2, o3);
        *(uint2*)(out1T + (size_t)q * 264 + c) = pk;
      }
    }
  }
  __syncthreads();

  // ---- q2 projection (waves 0,1): W2 A-frag 32x32x16 bf16, pre-scaled ----
  if (w < 2) {
    const int qh = w;
    v16f qacc = (v16f)(0.f);
#pragma unroll
    for (int s = 0; s < 16; ++s) {
      v8s af = *(const v8s*)(W2g + (size_t)(s * 64 + lane) * 8);
      v8s bf = *(const v8s*)(out1T + (size_t)(qh * 32 + l31) * 264 + s * 16 + lh * 8);
      qacc = __builtin_amdgcn_mfma_f32_32x32x16_bf16(af, bf, qacc, 0, 0, 0);
    }
#pragma unroll
    for (int rg = 0; rg < 4; ++rg) {
      const int o = 8 * rg + 4 * lh;
      uint2 pk;
      pk.x = pack_bf16(qacc[rg * 4 + 0] + q2b[o + 0] * LOG2E, qacc[rg * 4 + 1] + q2b[o + 1] * LOG2E);
      pk.y = pack_bf16(qacc[rg * 4 + 2] + q2b[o + 2] * LOG2E, qacc[rg * 4 + 3] + q2b[o + 3] * LOG2E);
      *(uint2*)(q2s + (size_t)(qh * 32 + l31) * 32 + o) = pk;
    }
  }
  __syncthreads();

  // ---- layer 2 ----
#pragma unroll
  for (int qt = 0; qt < 4; ++qt)
    qf[qt] = *(const v8s*)(q2s + (qt * 16 + r15) * 32 + quad * 8);
  acc[0] = (v16f)(0.f); acc[1] = (v16f)(0.f);
#pragma unroll
  for (int qt = 0; qt < 4; ++qt) lsum[qt] = 0.f;
  max_pass16(K2p, qf, w, lane, lbuf, m);
  attn_loop(K2p, V2p, P, qf, m, w, lane, acc, lsum);
  if (w < 8) {
#pragma unroll
    for (int qt = 0; qt < 4; ++qt) {
      lsum[qt] += __shfl_xor(lsum[qt], 16);
      lsum[qt] += __shfl_xor(lsum[qt], 32);
    }
    if (lane < 16) {
#pragma unroll
      for (int qt = 0; qt < 4; ++qt) lbuf[w][qt * 16 + lane] = lsum[qt];
    }
  }
  __syncthreads();
#pragma unroll
  for (int qh = 0; qh < 2; ++qh) {
    const int q = qh * 32 + l31;
    float d = 0.f;
#pragma unroll
    for (int ww = 0; ww < 8; ++ww) d += lbuf[ww][q];
    rinv[qh] = 1.0f / d;
  }
  if (w >= 8) {  // layer-2 epilogue by PV waves
    const int cw = (w - 8) * 32;
#pragma unroll
    for (int qh = 0; qh < 2; ++qh) {
      const int q = qh * 32 + l31;
#pragma unroll
      for (int rg = 0; rg < 4; ++rg) {
        const int c = cw + 8 * rg + 4 * lh;
#pragma unroll
        for (int i = 0; i < 4; ++i) {
          float res = bf2f(out1T[(size_t)q * 264 + c + i]);
          outp[((size_t)b * CDIM + c + i) * NSEQ + n0 + q] =
              g2 * (acc[qh][rg * 4 + i] * rinv[qh]) + res;
        }
      }
    }
  }
}

extern "C" void kernel_launch(void* const* d_in, const int* in_sizes, int n_in,
                              void* d_out, int out_size, void* d_ws, size_t ws_size,
                              hipStream_t stream) {
  const float* x   = (const float*)d_in[0];
  const float* y   = (const float*)d_in[1];
  const float* z   = (const float*)d_in[2];
  const float* q1w = (const float*)d_in[3];
  const float* q1b = (const float*)d_in[4];
  const float* k1w = (const float*)d_in[5];
  const float* k1b = (const float*)d_in[6];
  const float* v1w = (const float*)d_in[7];
  const float* v1b = (const float*)d_in[8];
  const float* g1  = (const float*)d_in[9];
  const float* q2w = (const float*)d_in[10];
  const float* q2b = (const float*)d_in[11];
  const float* k2w = (const float*)d_in[12];
  const float* k2b = (const float*)d_in[13];
  const float* v2w = (const float*)d_in[14];
  const float* v2b = (const float*)d_in[15];
  const float* g2  = (const float*)d_in[16];
  char* ws = (char*)d_ws;
  unsigned short* Wbf = (unsigned short*)(ws);             // 327,680 B
  unsigned short* Q1  = (unsigned short*)(ws + 327680);    // 1 MB
  unsigned short* K1  = (unsigned short*)(ws + 1376256);   // 1 MB
  unsigned short* K2  = (unsigned short*)(ws + 2424832);   // 1 MB
  unsigned char*  V1  = (unsigned char*)(ws + 3473408);    // 4 MB (fp8)
  unsigned char*  V2  = (unsigned char*)(ws + 7667712);    // 4 MB (fp8) -> 11.9 MB total
  float* outp = (float*)d_out;

  convw_kernel<<<dim3(80), 256, 0, stream>>>(q1w, k1w, k2w, q2w, v1w, v2w, Wbf);
  prep_kernel<<<dim3(64, 4, 3), 256, 0, stream>>>(x, y, z, Wbf, q1b, k1b, k2b, v1b,
                                                  v2b, Q1, K1, K2, V1, V2);
  fused_attn_kernel<<<dim3(256), 1024, 0, stream>>>(Q1, K1, V1, K2, V2, Wbf + 24576, x,
                                                    q2b, g1, g2, outp);
}

// Round 8
// 207.244 us; speedup vs baseline: 2.2718x; 1.0174x over previous
//
#include <hip/hip_runtime.h>
#include <hip/hip_bf16.h>

#define NSEQ 4096
#define CDIM 256
#define CQKD 32
#define LOG2E 1.4426950408889634f

typedef float v4f __attribute__((ext_vector_type(4)));
typedef float v16f __attribute__((ext_vector_type(16)));
typedef short v8s __attribute__((ext_vector_type(8)));
typedef unsigned long long u64;

__device__ __forceinline__ float exp2_(float x) {
#if __has_builtin(__builtin_amdgcn_exp2f)
  return __builtin_amdgcn_exp2f(x);
#else
  float r;
  __asm__("v_exp_f32 %0, %1" : "=v"(r) : "v"(x));
  return r;
#endif
}

__device__ __forceinline__ unsigned short f2bf(float x) {
  unsigned u = __builtin_bit_cast(unsigned, x);
  unsigned r = (u + 0x7FFFu + ((u >> 16) & 1u)) >> 16;
  return (unsigned short)r;
}
__device__ __forceinline__ float bf2f(unsigned short s) {
  unsigned u = ((unsigned)s) << 16;
  return __builtin_bit_cast(float, u);
}
__device__ __forceinline__ unsigned int pack_bf16(float a, float b) {
#if __has_builtin(__builtin_amdgcn_cvt_pk_bf16_f32)
  typedef __bf16 v2bf __attribute__((ext_vector_type(2)));
  v2bf r = __builtin_amdgcn_cvt_pk_bf16_f32(a, b);
  return __builtin_bit_cast(unsigned int, r);
#else
  return ((unsigned)f2bf(b) << 16) | (unsigned)f2bf(a);
#endif
}

// fp8 e4m3fn (OCP) encode, software fallback
__device__ __forceinline__ unsigned char f2e4m3(float x) {
  unsigned u = __builtin_bit_cast(unsigned, x);
  unsigned s = (u >> 24) & 0x80u;
  unsigned au = u & 0x7fffffffu;
  if (au > 0x43e00000u) return (unsigned char)(s | 0x7eu);  // clamp to 448
  if (au < 0x3c800000u) {                                   // subnormal range (<2^-6)
    float ax = __builtin_bit_cast(float, au);
    int q = (int)(ax * 512.0f + 0.5f);
    if (q > 7) q = 7;
    return (unsigned char)(s | (unsigned)q);
  }
  int e = (int)((au >> 23) & 0xffu) - 127 + 7;
  unsigned m = au & 0x7fffffu;
  unsigned mr = m + 0x7ffffu + ((m >> 20) & 1u);
  if (mr >= 0x800000u) { mr -= 0x800000u; e += 1; if (e >= 16) return (unsigned char)(s | 0x7e); }
  return (unsigned char)(s | ((unsigned)e << 3) | (mr >> 20));
}
__device__ __forceinline__ unsigned int pack4_fp8(float a, float b, float c, float d) {
#if __has_builtin(__builtin_amdgcn_cvt_pk_fp8_f32)
  int v = 0;
  v = __builtin_amdgcn_cvt_pk_fp8_f32(a, b, v, false);
  v = __builtin_amdgcn_cvt_pk_fp8_f32(c, d, v, true);
  return (unsigned int)v;
#else
  return (unsigned)f2e4m3(a) | ((unsigned)f2e4m3(b) << 8) |
         ((unsigned)f2e4m3(c) << 16) | ((unsigned)f2e4m3(d) << 24);
#endif
}

// ---------------- weight convert+frag-pack (bf16) ----------------
__global__ __launch_bounds__(256) void convw_kernel(
    const float* __restrict__ q1w, const float* __restrict__ k1w,
    const float* __restrict__ k2w, const float* __restrict__ q2w,
    const float* __restrict__ v1w, const float* __restrict__ v2w,
    unsigned short* __restrict__ W) {
  const int s = blockIdx.x * 256 + threadIdx.x;  // v8s slot, 20480 total
  const float* src;
  int o, ch0;
  size_t obase;
  float scale = 1.0f;
  if (s < 3072) {
    const int wsel = s >> 10, r = s & 1023;
    src = wsel == 0 ? q1w : (wsel == 1 ? k1w : k2w);
    const int ot = r >> 9, cb = (r >> 6) & 7, lane = r & 63;
    o = ot * 16 + (lane & 15);
    ch0 = cb * 32 + ((lane >> 4) & 3) * 8;
    obase = (size_t)wsel * 8192 + (size_t)r * 8;
  } else if (s < 19456) {
    const int s2 = s - 3072, which = s2 >> 13, r = s2 & 8191;
    src = which == 0 ? v1w : v2w;
    const int ot = r >> 9, cb = (r >> 6) & 7, lane = r & 63;
    o = ot * 16 + (lane & 15);
    ch0 = cb * 32 + ((lane >> 4) & 3) * 8;
    obase = 32768 + (size_t)which * 65536 + (size_t)r * 8;
  } else {
    const int r = s - 19456;
    src = q2w;
    const int lane = r & 63;
    o = lane & 31;
    ch0 = (r >> 6) * 16 + (lane >> 5) * 8;
    obase = 24576 + (size_t)r * 8;
    scale = LOG2E;
  }
#pragma unroll
  for (int j = 0; j < 8; ++j)
    W[obase + j] = f2bf(src[o * CDIM + ch0 + j] * scale);
}

// ---------------- prep: transpose + Q/K/V projections (V emitted fp8) ----------------
__global__ __launch_bounds__(256) void prep_kernel(
    const float* __restrict__ x, const float* __restrict__ y,
    const float* __restrict__ z, const unsigned short* __restrict__ Wbf,
    const float* __restrict__ q1b, const float* __restrict__ k1b,
    const float* __restrict__ k2b, const float* __restrict__ v1b,
    const float* __restrict__ v2b, unsigned short* __restrict__ Q1,
    unsigned short* __restrict__ K1, unsigned short* __restrict__ K2,
    unsigned char* __restrict__ V1, unsigned char* __restrict__ V2) {
  __shared__ unsigned short t[256][72];  // staging [ch][n] bf16; reused as fp8 Vt
  __shared__ unsigned short Kt[64][40];
  const int src = blockIdx.z;
  const float* in = src == 0 ? x : (src == 1 ? y : z);
  const int b = blockIdx.y;
  const int n0 = blockIdx.x * 64;
  const int tid = threadIdx.x, lane = tid & 63, w = tid >> 6;
  const int quad = lane >> 4, r15 = lane & 15, l31 = lane & 31, lh = lane >> 5;
  const float* ip = in + (size_t)(b * CDIM) * NSEQ + n0;
  {
    const int chb = tid >> 4, c4 = (tid & 15) * 4;
#pragma unroll
    for (int p = 0; p < 16; ++p) {
      const int ch = p * 16 + chb;
      float4 v = *(const float4*)(ip + (size_t)ch * NSEQ + c4);
      uint2 pk;
      pk.x = pack_bf16(v.x, v.y);
      pk.y = pack_bf16(v.z, v.w);
      *(uint2*)&t[ch][c4] = pk;
    }
  }
  __syncthreads();
  v8s af[8];
#pragma unroll
  for (int cb = 0; cb < 8; ++cb) {
    union { unsigned short e[8]; v8s v; } u;
#pragma unroll
    for (int j = 0; j < 8; ++j) u.e[j] = t[cb * 32 + quad * 8 + j][w * 16 + r15];
    af[cb] = u.v;
  }
  const int nt = blockIdx.x * 4 + w;
  const unsigned short* Wqk = Wbf + src * 8192;
  v4f a0 = {0.f, 0.f, 0.f, 0.f}, a1 = a0;
#pragma unroll
  for (int cb = 0; cb < 8; ++cb) {
    v8s b0 = *(const v8s*)(Wqk + (size_t)cb * 512 + lane * 8);
    v8s b1 = *(const v8s*)(Wqk + (size_t)(8 + cb) * 512 + lane * 8);
    a0 = __builtin_amdgcn_mfma_f32_16x16x32_bf16(af[cb], b0, a0, 0, 0, 0);
    a1 = __builtin_amdgcn_mfma_f32_16x16x32_bf16(af[cb], b1, a1, 0, 0, 0);
  }
  if (src == 0) {
#pragma unroll
    for (int r = 0; r < 4; ++r) {
      Q1[((size_t)b * NSEQ + nt * 16 + quad * 4 + r) * CQKD + r15] =
          f2bf((a0[r] + q1b[r15]) * LOG2E);
      Q1[((size_t)b * NSEQ + nt * 16 + quad * 4 + r) * CQKD + 16 + r15] =
          f2bf((a1[r] + q1b[16 + r15]) * LOG2E);
    }
    return;
  }
  const float* kbias = src == 1 ? k1b : k2b;
#pragma unroll
  for (int r = 0; r < 4; ++r) {
    Kt[w * 16 + quad * 4 + r][r15] = f2bf(a0[r] + kbias[r15]);
    Kt[w * 16 + quad * 4 + r][16 + r15] = f2bf(a1[r] + kbias[16 + r15]);
  }
  const unsigned short* Wv = Wbf + 32768 + (src - 1) * 65536;
  const float* vbias = src == 1 ? v1b : v2b;
  v4f vacc[16];
#pragma unroll
  for (int ot = 0; ot < 16; ++ot) vacc[ot] = (v4f){0.f, 0.f, 0.f, 0.f};
#pragma unroll
  for (int cb = 0; cb < 8; ++cb) {
    const v8s afc = af[cb];
#pragma unroll
    for (int ot = 0; ot < 16; ++ot) {
      v8s bf = *(const v8s*)(Wv + (size_t)(ot * 8 + cb) * 512 + lane * 8);
      vacc[ot] = __builtin_amdgcn_mfma_f32_16x16x32_bf16(afc, bf, vacc[ot], 0, 0, 0);
    }
  }
  __syncthreads();  // staging reads done -> reuse t as fp8 Vt (rows 72 B)
  unsigned char* Vt8 = (unsigned char*)t;
#pragma unroll
  for (int ot = 0; ot < 16; ++ot) {
    const int ch = ot * 16 + r15;
    const float bv = vbias[ch];
    *(unsigned int*)&Vt8[(size_t)ch * 72 + w * 16 + quad * 4] =
        pack4_fp8(vacc[ot][0] + bv, vacc[ot][1] + bv, vacc[ot][2] + bv, vacc[ot][3] + bv);
  }
  {
    unsigned short* Kout = (src == 1 ? K1 : K2) + (size_t)b * (NSEQ / 16) * 512;
    *(v8s*)(Kout + ((size_t)nt * 64 + lane) * 8) = *(const v8s*)&Kt[w * 16 + r15][quad * 8];
  }
  __syncthreads();  // Vt complete
  unsigned char* Vout = (src == 1 ? V1 : V2) + (size_t)b * (NSEQ / 16) * 8 * 512;
#pragma unroll
  for (int chb = 0; chb < 8; ++chb)
    *(u64*)(Vout + (((size_t)nt * 8 + chb) * 64 + lane) * 8) =
        *(const u64*)&Vt8[(size_t)(chb * 32 + l31) * 72 + w * 16 + lh * 8];
}

// ---------------- fused double attention: spin-flag producer/consumer ----------------
// 1024 thr = 16 waves, 64 q/block, grid 256 (1 block/CU, 4 waves/SIMD: 2S+2PV).
// NO collective barrier in the K-loop. P is an 8-tile (4-pair) LDS ring.
// Per slot s: prod_cnt[s] (ds_add by each S wave after lgkmcnt(0)) and
// cons_cnt[s] (ds_add by each PV wave after its reads). S waves run up to 4
// pairs ahead; each wave stalls only on its own dependency. Per-q global max
// from 16-wave max_pass keeps exp2(s-m) in (0,1] -> e4m3-safe.

__device__ __forceinline__ void poll_ge(const unsigned* p, unsigned target) {
  for (int i = 0; i < (1 << 20); ++i) {
    unsigned v = __hip_atomic_load(p, __ATOMIC_RELAXED, __HIP_MEMORY_SCOPE_WORKGROUP);
    if (v >= target) break;
    __builtin_amdgcn_s_sleep(1);
  }
  __builtin_amdgcn_sched_barrier(0);           // no code motion across the wait
  __asm__ __volatile__("" ::: "memory");
}
__device__ __forceinline__ void signal_cnt(unsigned* p, int lane) {
  __asm__ __volatile__("s_waitcnt lgkmcnt(0)" ::: "memory");  // LDS ops drained
  __builtin_amdgcn_sched_barrier(0);
  if (lane == 0)
    __hip_atomic_fetch_add(p, 1u, __ATOMIC_RELAXED, __HIP_MEMORY_SCOPE_WORKGROUP);
}

__device__ __forceinline__ void max_pass16(
    const unsigned short* __restrict__ Kp, const v8s qf[4], int w, int lane,
    float (*lbuf)[64], float m[4]) {
  const v4f vzero4 = {0.f, 0.f, 0.f, 0.f};
  const int r15 = lane & 15;
  const unsigned short* Kl = Kp + (size_t)w * 512 + lane * 8;
  v8s kA = *(const v8s*)(Kl);
  v8s kB = *(const v8s*)(Kl + 8192);
#pragma unroll
  for (int qt = 0; qt < 4; ++qt) m[qt] = -3.0e38f;
#pragma unroll 2
  for (int kt = 0; kt < 16; ++kt) {
    v8s kC = *(const v8s*)(Kl + (size_t)((kt + 2) & 15) * 8192);  // depth-2 prefetch
#pragma unroll
    for (int qt = 0; qt < 4; ++qt) {
      v4f st = __builtin_amdgcn_mfma_f32_16x16x32_bf16(kA, qf[qt], vzero4, 0, 0, 0);
      m[qt] = fmaxf(m[qt], fmaxf(fmaxf(st[0], st[1]), fmaxf(st[2], st[3])));
    }
    kA = kB;
    kB = kC;
  }
#pragma unroll
  for (int qt = 0; qt < 4; ++qt) {
    m[qt] = fmaxf(m[qt], __shfl_xor(m[qt], 16));
    m[qt] = fmaxf(m[qt], __shfl_xor(m[qt], 32));
  }
  if (lane < 16) {
#pragma unroll
    for (int qt = 0; qt < 4; ++qt) lbuf[w][qt * 16 + lane] = m[qt];
  }
  __syncthreads();
#pragma unroll
  for (int qt = 0; qt < 4; ++qt) {
    float mm = lbuf[0][qt * 16 + r15];
#pragma unroll
    for (int ww = 1; ww < 16; ++ww) mm = fmaxf(mm, lbuf[ww][qt * 16 + r15]);
    m[qt] = mm;
  }
  __syncthreads();
}

__device__ __forceinline__ void s_phase(
    unsigned char* __restrict__ P, int pbuf, const v8s kf, const v8s qf[4],
    const float m[4], int w, int lane, float lsum[4]) {
  const v4f vzero4 = {0.f, 0.f, 0.f, 0.f};
  const int quad = lane >> 4, r15 = lane & 15;
  unsigned char* pw = P + pbuf * 8704 + w * 16 + quad * 4;
#pragma unroll
  for (int qt = 0; qt < 4; ++qt) {
    v4f st = __builtin_amdgcn_mfma_f32_16x16x32_bf16(kf, qf[qt], vzero4, 0, 0, 0);
    float e0 = exp2_(st[0] - m[qt]), e1 = exp2_(st[1] - m[qt]);
    float e2 = exp2_(st[2] - m[qt]), e3 = exp2_(st[3] - m[qt]);
    lsum[qt] += (e0 + e1) + (e2 + e3);
    *(unsigned int*)(pw + (size_t)(qt * 16 + r15) * 136) = pack4_fp8(e0, e1, e2, e3);
  }
}

__device__ __forceinline__ void pv_tile(
    const unsigned char* __restrict__ P, int pbuf, const u64 vf[8], int lane,
    v16f acc[2]) {
  const int l31 = lane & 31, lh = lane >> 5;
  const unsigned char* pb = P + pbuf * 8704;
  __builtin_amdgcn_s_setprio(1);
#pragma unroll
  for (int s = 0; s < 8; ++s) {
    long pf0 = (long)*(const u64*)(pb + (size_t)l31 * 136 + s * 16 + lh * 8);
    long pf1 = (long)*(const u64*)(pb + (size_t)(32 + l31) * 136 + s * 16 + lh * 8);
    acc[0] = __builtin_amdgcn_mfma_f32_32x32x16_fp8_fp8((long)vf[s], pf0, acc[0], 0, 0, 0);
    acc[1] = __builtin_amdgcn_mfma_f32_32x32x16_fp8_fp8((long)vf[s], pf1, acc[1], 0, 0, 0);
  }
  __builtin_amdgcn_s_setprio(0);
}

__device__ __forceinline__ void attn_loop(
    const unsigned short* __restrict__ Kp, const unsigned char* __restrict__ Vp,
    unsigned char* __restrict__ P, unsigned* __restrict__ prod_cnt,
    unsigned* __restrict__ cons_cnt, const v8s qf[4], const float m[4], int w,
    int lane, v16f acc[2], float lsum[4]) {
  if (w < 8) {
    // ---- S producer: pairs 0..15 into 4-pair ring ----
    const unsigned short* Kl = Kp + (size_t)w * 512 + lane * 8;
    v8s k0 = *(const v8s*)(Kl);
    v8s k1 = *(const v8s*)(Kl + 4096);
#pragma unroll 1
    for (int p = 0; p < 16; ++p) {
      const int slot = p & 3;
      const unsigned it = (unsigned)(p >> 2);
      // prefetch next pair's K while (possibly) waiting
      v8s kn0 = *(const v8s*)(Kl + (size_t)((2 * p + 2) & 31) * 4096);
      v8s kn1 = *(const v8s*)(Kl + (size_t)((2 * p + 3) & 31) * 4096);
      poll_ge(&cons_cnt[slot], 8u * it);  // slot free (consumers done w/ pair p-4)
      s_phase(P, 2 * slot, k0, qf, m, w, lane, lsum);
      s_phase(P, 2 * slot + 1, k1, qf, m, w, lane, lsum);
      signal_cnt(&prod_cnt[slot], lane);
      k0 = kn0;
      k1 = kn1;
    }
  } else {
    // ---- PV consumer: pairs 0..15 ----
    const unsigned char* Vl = Vp + (size_t)(w - 8) * 512 + lane * 8;
    u64 v0[8], v1[8];
#pragma unroll
    for (int s = 0; s < 8; ++s) v0[s] = *(const u64*)(Vl + (size_t)s * 4096);
#pragma unroll
    for (int s = 0; s < 8; ++s) v1[s] = *(const u64*)(Vl + 32768 + (size_t)s * 4096);
#pragma unroll 1
    for (int p = 0; p < 16; ++p) {
      const int slot = p & 3;
      const unsigned it = (unsigned)(p >> 2);
      poll_ge(&prod_cnt[slot], 8u * (it + 1));  // pair p fully produced
      pv_tile(P, 2 * slot, v0, lane, acc);  // tile 2p
      // prefetch V(2p+2) (issued after v0's MFMA operands are read)
#pragma unroll
      for (int s = 0; s < 8; ++s)
        v0[s] = *(const u64*)(Vl + (size_t)((2 * p + 2) & 31) * 32768 + s * 4096);
      pv_tile(P, 2 * slot + 1, v1, lane, acc);  // tile 2p+1
#pragma unroll
      for (int s = 0; s < 8; ++s)
        v1[s] = *(const u64*)(Vl + (size_t)((2 * p + 3) & 31) * 32768 + s * 4096);
      signal_cnt(&cons_cnt[slot], lane);  // P reads drained -> slot reusable
    }
  }
}

__global__ __launch_bounds__(1024, 4) void fused_attn_kernel(
    const unsigned short* __restrict__ Q1g, const unsigned short* __restrict__ K1g,
    const unsigned char* __restrict__ V1g, const unsigned short* __restrict__ K2g,
    const unsigned char* __restrict__ V2g, const unsigned short* __restrict__ W2g,
    const float* __restrict__ x, const float* __restrict__ q2b,
    const float* __restrict__ g1p, const float* __restrict__ g2p,
    float* __restrict__ outp) {
  __shared__ __align__(16) unsigned char P[8 * 8704];        // 69.6 KB fp8 P ring
  __shared__ __align__(16) unsigned short out1T[64 * 264];   // 33.8 KB [q][c] bf16
  __shared__ __align__(16) unsigned short q2s[64 * 32];      // 4 KB [q][o]
  __shared__ float lbuf[16][64];                             // 4 KB
  __shared__ unsigned prod_cnt[4], cons_cnt[4];

  const int tid = threadIdx.x;
  const int lane = tid & 63;
  const int w = tid >> 6;        // 0..15; 0-7 = S producers, 8-15 = PV consumers
  const int quad = lane >> 4;
  const int r15 = lane & 15;
  const int l31 = lane & 31, lh = lane >> 5;
  const int b = blockIdx.x & 3;
  const int n0 = (blockIdx.x >> 2) * 64;

  const float g1 = g1p[0];
  const float g2 = g2p[0];

  const unsigned short* Qp  = Q1g + (size_t)b * NSEQ * CQKD;
  const unsigned short* K1p = K1g + (size_t)b * (NSEQ / 16) * 512;
  const unsigned short* K2p = K2g + (size_t)b * (NSEQ / 16) * 512;
  const unsigned char* V1p  = V1g + (size_t)b * (NSEQ / 16) * 8 * 512;
  const unsigned char* V2p  = V2g + (size_t)b * (NSEQ / 16) * 8 * 512;

  v8s qf[4];
#pragma unroll
  for (int qt = 0; qt < 4; ++qt)
    qf[qt] = *(const v8s*)(Qp + (n0 + qt * 16 + r15) * CQKD + quad * 8);

  v16f acc[2];
  float lsum[4] = {0.f, 0.f, 0.f, 0.f};
  float m[4];
  acc[0] = (v16f)(0.f); acc[1] = (v16f)(0.f);

  // ---- layer 1 ----
  if (tid < 4) { prod_cnt[tid] = 0; cons_cnt[tid] = 0; }
  max_pass16(K1p, qf, w, lane, lbuf, m);  // internal syncthreads orders the zeroing
  attn_loop(K1p, V1p, P, prod_cnt, cons_cnt, qf, m, w, lane, acc, lsum);
  // lsum reduce: S-waves only hold it
  if (w < 8) {
#pragma unroll
    for (int qt = 0; qt < 4; ++qt) {
      lsum[qt] += __shfl_xor(lsum[qt], 16);
      lsum[qt] += __shfl_xor(lsum[qt], 32);
    }
    if (lane < 16) {
#pragma unroll
      for (int qt = 0; qt < 4; ++qt) lbuf[w][qt * 16 + lane] = lsum[qt];
    }
  }
  __syncthreads();
  float rinv[2];
#pragma unroll
  for (int qh = 0; qh < 2; ++qh) {
    const int q = qh * 32 + l31;
    float d = 0.f;
#pragma unroll
    for (int ww = 0; ww < 8; ++ww) d += lbuf[ww][q];
    rinv[qh] = 1.0f / d;
  }
  if (w >= 8) {  // layer-1 epilogue by PV waves (they hold acc)
    const int cw = (w - 8) * 32;
#pragma unroll
    for (int qh = 0; qh < 2; ++qh) {
      const int q = qh * 32 + l31;
#pragma unroll
      for (int rg = 0; rg < 4; ++rg) {
        const int c = cw + 8 * rg + 4 * lh;
        float o0 = g1 * (acc[qh][rg * 4 + 0] * rinv[qh]) + x[((size_t)b * CDIM + c + 0) * NSEQ + n0 + q];
        float o1 = g1 * (acc[qh][rg * 4 + 1] * rinv[qh]) + x[((size_t)b * CDIM + c + 1) * NSEQ + n0 + q];
        float o2 = g1 * (acc[qh][rg * 4 + 2] * rinv[qh]) + x[((size_t)b * CDIM + c + 2) * NSEQ + n0 + q];
        float o3 = g1 * (acc[qh][rg * 4 + 3] * rinv[qh]) + x[((size_t)b * CDIM + c + 3) * NSEQ + n0 + q];
        uint2 pk;
        pk.x = pack_bf16(o0, o1);
        pk.y = pack_bf16(o2, o3);
        *(uint2*)(out1T + (size_t)q * 264 + c) = pk;
      }
    }
  }
  __syncthreads();

  // ---- q2 projection (waves 0,1): W2 A-frag 32x32x16 bf16, pre-scaled ----
  if (w < 2) {
    const int qh = w;
    v16f qacc = (v16f)(0.f);
#pragma unroll
    for (int s = 0; s < 16; ++s) {
      v8s af = *(const v8s*)(W2g + (size_t)(s * 64 + lane) * 8);
      v8s bf = *(const v8s*)(out1T + (size_t)(qh * 32 + l31) * 264 + s * 16 + lh * 8);
      qacc = __builtin_amdgcn_mfma_f32_32x32x16_bf16(af, bf, qacc, 0, 0, 0);
    }
#pragma unroll
    for (int rg = 0; rg < 4; ++rg) {
      const int o = 8 * rg + 4 * lh;
      uint2 pk;
      pk.x = pack_bf16(qacc[rg * 4 + 0] + q2b[o + 0] * LOG2E, qacc[rg * 4 + 1] + q2b[o + 1] * LOG2E);
      pk.y = pack_bf16(qacc[rg * 4 + 2] + q2b[o + 2] * LOG2E, qacc[rg * 4 + 3] + q2b[o + 3] * LOG2E);
      *(uint2*)(q2s + (size_t)(qh * 32 + l31) * 32 + o) = pk;
    }
  }
  __syncthreads();

  // ---- layer 2 ----
#pragma unroll
  for (int qt = 0; qt < 4; ++qt)
    qf[qt] = *(const v8s*)(q2s + (qt * 16 + r15) * 32 + quad * 8);
  acc[0] = (v16f)(0.f); acc[1] = (v16f)(0.f);
#pragma unroll
  for (int qt = 0; qt < 4; ++qt) lsum[qt] = 0.f;
  if (tid < 4) { prod_cnt[tid] = 0; cons_cnt[tid] = 0; }
  max_pass16(K2p, qf, w, lane, lbuf, m);  // internal syncthreads orders the zeroing
  attn_loop(K2p, V2p, P, prod_cnt, cons_cnt, qf, m, w, lane, acc, lsum);
  if (w < 8) {
#pragma unroll
    for (int qt = 0; qt < 4; ++qt) {
      lsum[qt] += __shfl_xor(lsum[qt], 16);
      lsum[qt] += __shfl_xor(lsum[qt], 32);
    }
    if (lane < 16) {
#pragma unroll
      for (int qt = 0; qt < 4; ++qt) lbuf[w][qt * 16 + lane] = lsum[qt];
    }
  }
  __syncthreads();
#pragma unroll
  for (int qh = 0; qh < 2; ++qh) {
    const int q = qh * 32 + l31;
    float d = 0.f;
#pragma unroll
    for (int ww = 0; ww < 8; ++ww) d += lbuf[ww][q];
    rinv[qh] = 1.0f / d;
  }
  if (w >= 8) {  // layer-2 epilogue by PV waves
    const int cw = (w - 8) * 32;
#pragma unroll
    for (int qh = 0; qh < 2; ++qh) {
      const int q = qh * 32 + l31;
#pragma unroll
      for (int rg = 0; rg < 4; ++rg) {
        const int c = cw + 8 * rg + 4 * lh;
#pragma unroll
        for (int i = 0; i < 4; ++i) {
          float res = bf2f(out1T[(size_t)q * 264 + c + i]);
          outp[((size_t)b * CDIM + c + i) * NSEQ + n0 + q] =
              g2 * (acc[qh][rg * 4 + i] * rinv[qh]) + res;
        }
      }
    }
  }
}

extern "C" void kernel_launch(void* const* d_in, const int* in_sizes, int n_in,
                              void* d_out, int out_size, void* d_ws, size_t ws_size,
                              hipStream_t stream) {
  const float* x   = (const float*)d_in[0];
  const float* y   = (const float*)d_in[1];
  const float* z   = (const float*)d_in[2];
  const float* q1w = (const float*)d_in[3];
  const float* q1b = (const float*)d_in[4];
  const float* k1w = (const float*)d_in[5];
  const float* k1b = (const float*)d_in[6];
  const float* v1w = (const float*)d_in[7];
  const float* v1b = (const float*)d_in[8];
  const float* g1  = (const float*)d_in[9];
  const float* q2w = (const float*)d_in[10];
  const float* q2b = (const float*)d_in[11];
  const float* k2w = (const float*)d_in[12];
  const float* k2b = (const float*)d_in[13];
  const float* v2w = (const float*)d_in[14];
  const float* v2b = (const float*)d_in[15];
  const float* g2  = (const float*)d_in[16];
  char* ws = (char*)d_ws;
  unsigned short* Wbf = (unsigned short*)(ws);             // 327,680 B
  unsigned short* Q1  = (unsigned short*)(ws + 327680);    // 1 MB
  unsigned short* K1  = (unsigned short*)(ws + 1376256);   // 1 MB
  unsigned short* K2  = (unsigned short*)(ws + 2424832);   // 1 MB
  unsigned char*  V1  = (unsigned char*)(ws + 3473408);    // 4 MB (fp8)
  unsigned char*  V2  = (unsigned char*)(ws + 7667712);    // 4 MB (fp8) -> 11.9 MB total
  float* outp = (float*)d_out;

  convw_kernel<<<dim3(80), 256, 0, stream>>>(q1w, k1w, k2w, q2w, v1w, v2w, Wbf);
  prep_kernel<<<dim3(64, 4, 3), 256, 0, stream>>>(x, y, z, Wbf, q1b, k1b, k2b, v1b,
                                                  v2b, Q1, K1, K2, V1, V2);
  fused_attn_kernel<<<dim3(256), 1024, 0, stream>>>(Q1, K1, V1, K2, V2, Wbf + 24576, x,
                                                    q2b, g1, g2, outp);
}